// Round 1
// baseline (77.073 us; speedup 1.0000x reference)
//
#include <hip/hip_runtime.h>
#include <hip/hip_fp16.h>

#define BB 2
#define LL 16
#define CC 16
#define HH 64
#define WW 64
#define HWSZ (HH * WW)

__device__ __forceinline__ float2 cvt2(unsigned int u) {
    __half2 h = *reinterpret_cast<const __half2*>(&u);
    return __half22float2(h);
}

// ---- prep: NCHW fp32 -> NHWC fp16 (pixel = 32B; 16B per 8-ch half) ----
__global__ __launch_bounds__(256) void gsp_prep(
    const float* __restrict__ images,  // (B, L, C, H, W)
    uint4* __restrict__ h16)           // (B*L, HW, 2) uint4 (8 fp16 each)
{
    const int gid  = blockIdx.x * 256 + threadIdx.x;  // 0..262143
    const int half = gid & 1;
    const int pix  = (gid >> 1) & (HWSZ - 1);
    const int bl   = gid >> 13;

    const float* src = images + (size_t)(bl * CC + half * 8) * HWSZ + pix;
    unsigned short hs[8];
    #pragma unroll
    for (int m = 0; m < 8; ++m) {
        __half h = __float2half(src[(size_t)m * HWSZ]);
        hs[m] = *reinterpret_cast<unsigned short*>(&h);
    }
    uint4 v;
    v.x = (unsigned)hs[0] | ((unsigned)hs[1] << 16);
    v.y = (unsigned)hs[2] | ((unsigned)hs[3] << 16);
    v.z = (unsigned)hs[4] | ((unsigned)hs[5] << 16);
    v.w = (unsigned)hs[6] | ((unsigned)hs[7] << 16);
    h16[((size_t)bl * HWSZ + pix) * 2 + half] = v;
}

// ---- main: block = (b, i, 64-px tile); lane = (px, xc, half). Per-thread
//      register cumsum of flows (no cum2 workspace). j-loop fully unrolled
//      (wave-uniform guards) so all gather loads can be hoisted/overlapped.
//      4 lanes of a pixel load contiguous 64B (both x-corners x both halves
//      of one y-corner); x-partials recombined via shfl_xor(2). ----
__global__ __launch_bounds__(256) void gsp_main(
    const float* __restrict__ flows,   // (B, L, 2, H, W)
    const uint4* __restrict__ h16,     // (B*L, HW, 2) uint4
    float* __restrict__ out)           // (B, L, C, H, W)
{
    const int idx  = blockIdx.x;                 // 2048 blocks, heavy i first
    const int i    = 15 - (idx >> 7);
    const int b    = (idx >> 6) & 1;
    const int tile = idx & 63;

    const int sub  = threadIdx.x & 3;            // (xc, half) within pixel
    const int half = sub & 1;
    const int xc   = sub >> 1;
    const int px   = tile * 64 + (threadIdx.x >> 2);
    const int h = px >> 6;
    const int w = px & (WW - 1);

    // per-thread cumsum of flows at this pixel (all 16 loads independent)
    float cx16[LL], cy16[LL];
    {
        const float* fb = flows + (size_t)b * LL * 2 * HWSZ + px;
        #pragma unroll
        for (int l = 0; l < LL; ++l) {
            cx16[l] = fb[(size_t)l * 2 * HWSZ];
            cy16[l] = fb[(size_t)l * 2 * HWSZ + HWSZ];
        }
        #pragma unroll
        for (int l = 1; l < LL; ++l) { cx16[l] += cx16[l - 1]; cy16[l] += cy16[l - 1]; }
    }

    const uint4* h16_b = h16 + (size_t)(b * LL) * HWSZ * 2;

    const float gxb = (w + 0.5f) * (2.0f / WW) - 1.0f;
    const float gyb = (h + 0.5f) * (2.0f / HH) - 1.0f;

    float cix = 0.0f, ciy = 0.0f;
    #pragma unroll
    for (int l = 0; l < LL; ++l) { if (l == i) { cix = cx16[l]; ciy = cy16[l]; } }

    float acc[8];
    #pragma unroll
    for (int m = 0; m < 8; ++m) acc[m] = 0.0f;

    #pragma unroll
    for (int j = 0; j < LL - 1; ++j) {
        if (j < i) {                             // wave-uniform guard
            float gx = gxb + (cix - cx16[j]);
            float gy = gyb + (ciy - cy16[j]);

            // gx = remainder(gx + 1, 2) - 1
            float tt = gx + 1.0f;
            tt = tt - floorf(tt * 0.5f) * 2.0f;
            gx = tt - 1.0f;

            const float ix = ((gx + 1.0f) * WW - 1.0f) * 0.5f;
            const float iy = ((gy + 1.0f) * HH - 1.0f) * 0.5f;
            const float x0f = floorf(ix);
            const float y0f = floorf(iy);
            const float fx = ix - x0f;
            const float fy = iy - y0f;
            const int x0 = (int)x0f;
            const int y0 = (int)y0f;

            // this lane's x-corner
            const int  xr = x0 + xc;
            const bool vx = (xr >= 0) && (xr < WW);
            const int  cx = min(max(xr, 0), WW - 1);
            const float wx = (xc ? fx : (1.0f - fx)) * (vx ? 1.0f : 0.0f);

            // y-corners
            const int y1i = y0 + 1;
            const bool vy0 = (y0 >= 0) && (y0 < HH);
            const bool vy1 = (y1i >= 0) && (y1i < HH);
            const int cy0 = min(max(y0, 0), HH - 1);
            const int cy1 = min(max(y1i, 0), HH - 1);

            const uint4* jb = h16_b + (size_t)j * HWSZ * 2;
            const uint4 v0 = jb[(cy0 * WW + cx) * 2 + half];
            const uint4 v1 = jb[(cy1 * WW + cx) * 2 + half];

            const float w0 = wx * (1.0f - fy) * (vy0 ? 1.0f : 0.0f);
            const float w1 = wx * fy * (vy1 ? 1.0f : 0.0f);

            {
                const float2 p0 = cvt2(v0.x), p1 = cvt2(v0.y);
                const float2 p2 = cvt2(v0.z), p3 = cvt2(v0.w);
                acc[0] += w0 * p0.x;  acc[1] += w0 * p0.y;
                acc[2] += w0 * p1.x;  acc[3] += w0 * p1.y;
                acc[4] += w0 * p2.x;  acc[5] += w0 * p2.y;
                acc[6] += w0 * p3.x;  acc[7] += w0 * p3.y;
            }
            {
                const float2 p0 = cvt2(v1.x), p1 = cvt2(v1.y);
                const float2 p2 = cvt2(v1.z), p3 = cvt2(v1.w);
                acc[0] += w1 * p0.x;  acc[1] += w1 * p0.y;
                acc[2] += w1 * p1.x;  acc[3] += w1 * p1.y;
                acc[4] += w1 * p2.x;  acc[5] += w1 * p2.y;
                acc[6] += w1 * p3.x;  acc[7] += w1 * p3.y;
            }
        }
    }

    // recombine the two x-corner partial sums (lanes differing in bit 1)
    #pragma unroll
    for (int m = 0; m < 8; ++m) acc[m] += __shfl_xor(acc[m], 2, 64);

    // this lane's output quad: q = half*2 + xc -> channels q*4 .. q*4+3
    float s0 = xc ? acc[4] : acc[0];
    float s1 = xc ? acc[5] : acc[1];
    float s2 = xc ? acc[6] : acc[2];
    float s3 = xc ? acc[7] : acc[3];

    // identity term (j == i, exact integer pixel centers), fp16 source
    {
        const uint2* h2 = (const uint2*)h16;
        const uint2 idv = h2[(((size_t)(b * LL + i) * HWSZ + px) * 2 + half) * 2 + xc];
        const float2 p0 = cvt2(idv.x), p1 = cvt2(idv.y);
        s0 += p0.x; s1 += p0.y; s2 += p1.x; s3 += p1.y;
    }

    const int q = half * 2 + xc;
    float* op = out + ((size_t)(b * LL + i) * CC + q * 4) * HWSZ + px;
    op[0 * HWSZ] = s0;
    op[1 * HWSZ] = s1;
    op[2 * HWSZ] = s2;
    op[3 * HWSZ] = s3;
}

extern "C" void kernel_launch(void* const* d_in, const int* in_sizes, int n_in,
                              void* d_out, int out_size, void* d_ws, size_t ws_size,
                              hipStream_t stream) {
    const float* flows  = (const float*)d_in[0];
    const float* images = (const float*)d_in[1];
    float* out = (float*)d_out;
    uint4* h16 = (uint4*)d_ws;                         // 4 MB

    gsp_prep<<<1024, 256, 0, stream>>>(images, h16);

    gsp_main<<<2048, 256, 0, stream>>>(flows, h16, out);
}

// Round 2
// 75.186 us; speedup vs baseline: 1.0251x; 1.0251x over previous
//
#include <hip/hip_runtime.h>
#include <hip/hip_fp16.h>

#define BB 2
#define LL 16
#define CC 16
#define HH 64
#define WW 64
#define HWSZ (HH * WW)

__device__ __forceinline__ float2 cvt2(unsigned int u) {
    __half2 h = *reinterpret_cast<const __half2*>(&u);
    return __half22float2(h);
}

// ---- prep: NCHW fp32 -> NHWC fp16 (pixel = 32B; 16B per 8-ch half) ----
__global__ __launch_bounds__(256) void gsp_prep(
    const float* __restrict__ images,  // (B, L, C, H, W)
    uint4* __restrict__ h16)           // (B*L, HW, 2) uint4 (8 fp16 each)
{
    const int gid  = blockIdx.x * 256 + threadIdx.x;  // 0..262143
    const int half = gid & 1;
    const int pix  = (gid >> 1) & (HWSZ - 1);
    const int bl   = gid >> 13;

    const float* src = images + (size_t)(bl * CC + half * 8) * HWSZ + pix;
    unsigned short hs[8];
    #pragma unroll
    for (int m = 0; m < 8; ++m) {
        __half h = __float2half(src[(size_t)m * HWSZ]);
        hs[m] = *reinterpret_cast<unsigned short*>(&h);
    }
    uint4 v;
    v.x = (unsigned)hs[0] | ((unsigned)hs[1] << 16);
    v.y = (unsigned)hs[2] | ((unsigned)hs[3] << 16);
    v.z = (unsigned)hs[4] | ((unsigned)hs[5] << 16);
    v.w = (unsigned)hs[6] | ((unsigned)hs[7] << 16);
    h16[((size_t)bl * HWSZ + pix) * 2 + half] = v;
}

// ---- main: block = (b, i, 64-px tile); lane = (px, xc, half).
//      XCD-swizzled: xcd = tile>>3, so each XCD's L2 holds one 8-row band
//      (~3.8 MB gather footprint incl. flow spill rows) for ALL i and b.
//      Heavy i dispatched first within each XCD (k ascending => i=15 first).
//      Output stores are nontemporal (write-once, keep L2 for h16). ----
__global__ __launch_bounds__(256) void gsp_main(
    const float* __restrict__ flows,   // (B, L, 2, H, W)
    const uint4* __restrict__ h16,     // (B*L, HW, 2) uint4
    float* __restrict__ out)           // (B, L, C, H, W)
{
    const int idx  = blockIdx.x;                 // 2048 blocks
    // XCD-aware decode: xcd = idx & 7 (round-robin dispatch), k = per-XCD seq.
    const int xcd  = idx & 7;
    const int k    = idx >> 3;                   // 0..255
    const int i    = 15 - (k >> 4);              // heavy i first per XCD
    const int b    = (k >> 3) & 1;
    const int tile = xcd * 8 + (k & 7);          // tile>>3 == xcd

    const int sub  = threadIdx.x & 3;            // (xc, half) within pixel
    const int half = sub & 1;
    const int xc   = sub >> 1;
    const int px   = tile * 64 + (threadIdx.x >> 2);
    const int h = px >> 6;
    const int w = px & (WW - 1);

    // per-thread cumsum of flows at this pixel (all 16 loads independent)
    float cx16[LL], cy16[LL];
    {
        const float* fb = flows + (size_t)b * LL * 2 * HWSZ + px;
        #pragma unroll
        for (int l = 0; l < LL; ++l) {
            cx16[l] = fb[(size_t)l * 2 * HWSZ];
            cy16[l] = fb[(size_t)l * 2 * HWSZ + HWSZ];
        }
        #pragma unroll
        for (int l = 1; l < LL; ++l) { cx16[l] += cx16[l - 1]; cy16[l] += cy16[l - 1]; }
    }

    const uint4* h16_b = h16 + (size_t)(b * LL) * HWSZ * 2;

    const float gxb = (w + 0.5f) * (2.0f / WW) - 1.0f;
    const float gyb = (h + 0.5f) * (2.0f / HH) - 1.0f;

    float cix = 0.0f, ciy = 0.0f;
    #pragma unroll
    for (int l = 0; l < LL; ++l) { if (l == i) { cix = cx16[l]; ciy = cy16[l]; } }

    float acc[8];
    #pragma unroll
    for (int m = 0; m < 8; ++m) acc[m] = 0.0f;

    #pragma unroll
    for (int j = 0; j < LL - 1; ++j) {
        if (j < i) {                             // wave-uniform guard
            float gx = gxb + (cix - cx16[j]);
            float gy = gyb + (ciy - cy16[j]);

            // gx = remainder(gx + 1, 2) - 1
            float tt = gx + 1.0f;
            tt = tt - floorf(tt * 0.5f) * 2.0f;
            gx = tt - 1.0f;

            const float ix = ((gx + 1.0f) * WW - 1.0f) * 0.5f;
            const float iy = ((gy + 1.0f) * HH - 1.0f) * 0.5f;
            const float x0f = floorf(ix);
            const float y0f = floorf(iy);
            const float fx = ix - x0f;
            const float fy = iy - y0f;
            const int x0 = (int)x0f;
            const int y0 = (int)y0f;

            // this lane's x-corner
            const int  xr = x0 + xc;
            const bool vx = (xr >= 0) && (xr < WW);
            const int  cx = min(max(xr, 0), WW - 1);
            const float wx = (xc ? fx : (1.0f - fx)) * (vx ? 1.0f : 0.0f);

            // y-corners
            const int y1i = y0 + 1;
            const bool vy0 = (y0 >= 0) && (y0 < HH);
            const bool vy1 = (y1i >= 0) && (y1i < HH);
            const int cy0 = min(max(y0, 0), HH - 1);
            const int cy1 = min(max(y1i, 0), HH - 1);

            const uint4* jb = h16_b + (size_t)j * HWSZ * 2;
            const uint4 v0 = jb[(cy0 * WW + cx) * 2 + half];
            const uint4 v1 = jb[(cy1 * WW + cx) * 2 + half];

            const float w0 = wx * (1.0f - fy) * (vy0 ? 1.0f : 0.0f);
            const float w1 = wx * fy * (vy1 ? 1.0f : 0.0f);

            {
                const float2 p0 = cvt2(v0.x), p1 = cvt2(v0.y);
                const float2 p2 = cvt2(v0.z), p3 = cvt2(v0.w);
                acc[0] += w0 * p0.x;  acc[1] += w0 * p0.y;
                acc[2] += w0 * p1.x;  acc[3] += w0 * p1.y;
                acc[4] += w0 * p2.x;  acc[5] += w0 * p2.y;
                acc[6] += w0 * p3.x;  acc[7] += w0 * p3.y;
            }
            {
                const float2 p0 = cvt2(v1.x), p1 = cvt2(v1.y);
                const float2 p2 = cvt2(v1.z), p3 = cvt2(v1.w);
                acc[0] += w1 * p0.x;  acc[1] += w1 * p0.y;
                acc[2] += w1 * p1.x;  acc[3] += w1 * p1.y;
                acc[4] += w1 * p2.x;  acc[5] += w1 * p2.y;
                acc[6] += w1 * p3.x;  acc[7] += w1 * p3.y;
            }
        }
    }

    // recombine the two x-corner partial sums (lanes differing in bit 1)
    #pragma unroll
    for (int m = 0; m < 8; ++m) acc[m] += __shfl_xor(acc[m], 2, 64);

    // this lane's output quad: q = half*2 + xc -> channels q*4 .. q*4+3
    float s0 = xc ? acc[4] : acc[0];
    float s1 = xc ? acc[5] : acc[1];
    float s2 = xc ? acc[6] : acc[2];
    float s3 = xc ? acc[7] : acc[3];

    // identity term (j == i, exact integer pixel centers), fp16 source
    {
        const uint2* h2 = (const uint2*)h16;
        const uint2 idv = h2[(((size_t)(b * LL + i) * HWSZ + px) * 2 + half) * 2 + xc];
        const float2 p0 = cvt2(idv.x), p1 = cvt2(idv.y);
        s0 += p0.x; s1 += p0.y; s2 += p1.x; s3 += p1.y;
    }

    const int q = half * 2 + xc;
    float* op = out + ((size_t)(b * LL + i) * CC + q * 4) * HWSZ + px;
    __builtin_nontemporal_store(s0, op + 0 * HWSZ);
    __builtin_nontemporal_store(s1, op + 1 * HWSZ);
    __builtin_nontemporal_store(s2, op + 2 * HWSZ);
    __builtin_nontemporal_store(s3, op + 3 * HWSZ);
}

extern "C" void kernel_launch(void* const* d_in, const int* in_sizes, int n_in,
                              void* d_out, int out_size, void* d_ws, size_t ws_size,
                              hipStream_t stream) {
    const float* flows  = (const float*)d_in[0];
    const float* images = (const float*)d_in[1];
    float* out = (float*)d_out;
    uint4* h16 = (uint4*)d_ws;                         // 4 MB

    gsp_prep<<<1024, 256, 0, stream>>>(images, h16);

    gsp_main<<<2048, 256, 0, stream>>>(flows, h16, out);
}